// Round 13
// baseline (1883.004 us; speedup 1.0000x reference)
//
#include <hip/hip_runtime.h>
#include <hip/hip_fp8.h>
#include <math.h>

#define BB 8
#define SS 2048
#define DD 512
#define LL 6
#define FFD 2048   // 4*D

typedef _Float16 half_t;
typedef __attribute__((ext_vector_type(8))) _Float16 half8;
typedef __attribute__((ext_vector_type(4))) _Float16 half4;
typedef __attribute__((ext_vector_type(4))) float f32x4;

enum { EPI_NONE = 0, EPI_RELU = 2, EPI_RES = 3, EPI_ATTN = 4, EPI_QKV = 5, EPI_PV = 6 };

__device__ __forceinline__ unsigned char f2e4m3(float v) {
    __hip_fp8_e4m3 f(v);
    return f.__x;
}

// ---------------- async global->LDS, 16B per lane ----------------
__device__ __forceinline__ void gl_lds16(const void* g, void* l) {
    __builtin_amdgcn_global_load_lds(
        (const __attribute__((address_space(1))) unsigned int*)g,
        (__attribute__((address_space(3))) unsigned int*)l,
        16, 0, 0);
}

__device__ __forceinline__ void blockReduce2(float& a, float& b, float* sm) {
#pragma unroll
    for (int off = 32; off; off >>= 1) {
        a += __shfl_down(a, off);
        b += __shfl_down(b, off);
    }
    int lane = threadIdx.x & 63;
    int w = threadIdx.x >> 6;
    if (lane == 0) { sm[w] = a; sm[4 + w] = b; }
    __syncthreads();
    a = sm[0] + sm[1] + sm[2] + sm[3];
    b = sm[4] + sm[5] + sm[6] + sm[7];
    __syncthreads();
}

// ---------------- encoder ----------------
__global__ __launch_bounds__(256) void encode_kernel(
    const float* __restrict__ z, const float* __restrict__ c,
    const float* __restrict__ enc_w, const float* __restrict__ enc_b,
    float* __restrict__ x)
{
    int idx = blockIdx.x * 256 + threadIdx.x;
    int d  = idx & (DD - 1);
    int bs = idx >> 9;
    int s  = bs & (SS - 1);
    float v = z[bs] * enc_w[2 * d] + c[bs] * enc_w[2 * d + 1] + enc_b[d];
    float div = expf(-(float)(d & ~1) * (9.210340371976184f / 512.0f));
    float ang = (float)s * div;
    v += (d & 1) ? cosf(ang) : sinf(ang);
    x[idx] = v;
}

// ---- one-shot weight conversion, ALL layers, float4->half4 vectorized ----
// 720896 quads/layer: [0,196608) -> wqkv, then 262144 -> f1, 262144 -> f2.
__global__ __launch_bounds__(256) void convert_all_kernel(
    const float* __restrict__ wq, const float* __restrict__ wk,
    const float* __restrict__ wv, const float* __restrict__ f1,
    const float* __restrict__ f2, half_t* __restrict__ wqkv6,
    half_t* __restrict__ f1h6, half_t* __restrict__ f2h6)
{
    const int NQ = DD * DD;                      // 262144
    const int l = blockIdx.x / 2816;
    const int q = (blockIdx.x % 2816) * 256 + threadIdx.x;  // quad in layer
    const int j4 = q * 4;
    const float* src;
    half_t* dst;
    int j;
    if (j4 < 3 * NQ) {
        const int which = j4 >> 18;
        j = j4 & (NQ - 1);
        src = ((which == 0) ? wq : (which == 1) ? wk : wv) + (size_t)l * NQ;
        dst = wqkv6 + (size_t)l * 3 * NQ + which * NQ;
    } else {
        int k = j4 - 3 * NQ;
        if (k < FFD * DD) {
            j = k;
            src = f1 + (size_t)l * FFD * DD;
            dst = f1h6 + (size_t)l * FFD * DD;
        } else {
            j = k - FFD * DD;
            src = f2 + (size_t)l * DD * FFD;
            dst = f2h6 + (size_t)l * DD * FFD;
        }
    }
    f32x4 v = *(const f32x4*)(src + j);
    half4 h;
    h[0] = (half_t)v[0]; h[1] = (half_t)v[1];
    h[2] = (half_t)v[2]; h[3] = (half_t)v[3];
    *(half4*)(dst + j) = h;
}

// ------- fallback per-layer conversion (used only if ws_size is tight) -------
__global__ __launch_bounds__(256) void convert_layer_kernel(
    const float* __restrict__ wq, const float* __restrict__ wk,
    const float* __restrict__ wv, const float* __restrict__ f1,
    const float* __restrict__ f2, half_t* __restrict__ wqkv,
    half_t* __restrict__ f1h, half_t* __restrict__ f2h)
{
    const int NQ = DD * DD;                      // 262144
    int i = blockIdx.x * 256 + threadIdx.x;
    if (i < 3 * NQ) {
        int which = i >> 18, j = i & (NQ - 1);
        const float* s = (which == 0) ? wq : (which == 1) ? wk : wv;
        wqkv[i] = (half_t)s[j];
    } else {
        int k = i - 3 * NQ;
        if (k < FFD * DD) f1h[k] = (half_t)f1[k];
        else              f2h[k - FFD * DD] = (half_t)f2[k - FFD * DD];
    }
}

// ---------------- attention bias tables: tbl[l][dist] ----------------
__global__ __launch_bounds__(256) void bias_table_kernel(
    const float* __restrict__ beta, float* __restrict__ tbl)
{
    int i = blockIdx.x * 256 + threadIdx.x;   // L*2048
    int l = i >> 11, d = i & (SS - 1);
    tbl[i] = beta[2 * l] * cosf(0.2617993877991494f * d)
           + beta[2 * l + 1] * cosf(0.008726646259971648f * d);
}

// ---------------- LN: dst(half) = LN(src)*w + b ----------------
__global__ __launch_bounds__(256) void ln_kernel(
    const float* __restrict__ src, const float* __restrict__ w,
    const float* __restrict__ b, half_t* __restrict__ dst)
{
    __shared__ float sm[8];
    size_t row = blockIdx.x;
    const float* p = src + row * DD;
    int t = threadIdx.x;
    float v0 = p[t], v1 = p[t + 256];
    float s = v0 + v1, sq = v0 * v0 + v1 * v1;
    blockReduce2(s, sq, sm);
    float mean = s * (1.0f / DD);
    float var  = sq * (1.0f / DD) - mean * mean;
    float rs   = rsqrtf(var + 1e-5f);
    dst[row * DD + t]       = (half_t)((v0 - mean) * rs * w[t] + b[t]);
    dst[row * DD + t + 256] = (half_t)((v1 - mean) * rs * w[t + 256] + b[t + 256]);
}

// -------- fused: x = LN(x, w1,b1); xn(half) = LN(x', w2,b2) --------
__global__ __launch_bounds__(256) void ln_ln_kernel(
    float* __restrict__ x,
    const float* __restrict__ w1, const float* __restrict__ b1,
    const float* __restrict__ w2, const float* __restrict__ b2,
    half_t* __restrict__ xn)
{
    __shared__ float sm[8];
    size_t row = blockIdx.x;
    int t = threadIdx.x;
    float v0 = x[row * DD + t];
    float v1 = x[row * DD + t + 256];
    float s = v0 + v1, sq = v0 * v0 + v1 * v1;
    blockReduce2(s, sq, sm);
    float mean = s * (1.0f / DD);
    float var  = sq * (1.0f / DD) - mean * mean;
    float rs   = rsqrtf(var + 1e-5f);
    float y0 = (v0 - mean) * rs * w1[t] + b1[t];
    float y1 = (v1 - mean) * rs * w1[t + 256] + b1[t + 256];
    x[row * DD + t]       = y0;
    x[row * DD + t + 256] = y1;
    s = y0 + y1; sq = y0 * y0 + y1 * y1;
    blockReduce2(s, sq, sm);
    mean = s * (1.0f / DD);
    var  = sq * (1.0f / DD) - mean * mean;
    rs   = rsqrtf(var + 1e-5f);
    xn[row * DD + t]       = (half_t)((y0 - mean) * rs * w2[t] + b2[t]);
    xn[row * DD + t + 256] = (half_t)((y1 - mean) * rs * w2[t + 256] + b2[t + 256]);
}

// ------------- 256-row MFMA NT GEMM, 8-wave phase-split schedule -------------
// Round 13 = round 12 + ONE change: the f16/BN=128 variant (FF2, QKV) issues
// ALL VM=6 stage calls for tile it+1 immediately after the iteration-top
// barrier, before phase-0 ds_reads. Phase-slot accounting (R12) showed FF2
// at ~4050 cyc/phase vs the ~1900 universal slot; discriminator vs QKV
// (same template): FF2's A-operand streams from HBM (FETCH 57MB), so the
// iteration-top vmcnt(0) on loads issued ~1 phase earlier exposes ~900+cyc
// HBM latency per iteration over only 2 phases. Front-loading makes the
// issue->drain distance ~2 full phases (~3800 cyc > HBM latency).
// WAR-safe: buffer cur^1 last read in iter it-1, fenced by the top barrier.
// All other variants and all numerics byte-identical to R12 (controls).
// LDS XOR swizzle: row r's 16-B chunk c stored at c^(r&7); staging
// pre-swizzles the global chunk per lane; reads XOR with (row&7).
// EPI_QKV : fp16 in -> fp8 out: Q(+bias), K(+biasK) row-major, V^T(+biasV)
// EPI_ATTN: fp8 in -> fp8 out: exp(min(v*alpha + tbl[|m-n|], 6))
// EPI_PV  : fp8 in -> fp32: ones-MFMA denominator, v*inv + x residual in-place
// EPI_RELU: fp16 in -> fp16: relu(v + bias[n])
// EPI_RES : fp16 in -> fp32: v + bias[n] + C (in-place residual)
template<typename TIN, int BN, int EPI, int SWZ = 0>
__global__ __launch_bounds__(512) void gemm256(
    const void* __restrict__ Ap, const void* __restrict__ Wp,
    const float* __restrict__ bias, void* __restrict__ Cp,
    int N, int K, float alpha,
    long long sA, long long sW, long long sC,
    const float* __restrict__ biasK, const float* __restrict__ biasV,
    unsigned char* __restrict__ Ck, unsigned char* __restrict__ Cv)
{
    constexpr int ES  = (int)sizeof(TIN);          // 2 (f16) or 1 (fp8)
    constexpr int MTW = (BN == 128) ? 4 : 8;       // m-tiles per wave
    constexpr int ASZ = 256 * 128;                 // one A buffer: 32 KB
    constexpr int BSZ = BN * 128;                  // one B buffer: 32/16 KB
    constexpr int VM  = 4 + BN / 64;               // stage calls per tile
    constexpr int PHS = (BN == 256) ? ((ES == 2) ? 4 : 8) : ((ES == 2) ? 2 : 4);
    __shared__ __align__(16) unsigned char As[2 * ASZ];
    __shared__ __align__(16) unsigned char Bs[2 * BSZ];

    int bxi, byi, bzi;
    if (SWZ == 1) {                                // XCD-bijective, 512 blocks
        const int id = blockIdx.x;
        const int ss2 = (id & 7) * 64 + (id >> 3);
        bxi = ss2 & 7; byi = (ss2 >> 3) & 7; bzi = ss2 >> 6;
    } else { bxi = blockIdx.x; byi = blockIdx.y; bzi = blockIdx.z; }

    const int z = bzi;
    const unsigned char* A = (const unsigned char*)Ap + (size_t)z * sA * ES;
    const unsigned char* W = (const unsigned char*)Wp + (size_t)z * sW * ES;
    float*  Cf = (float*)Cp  + (size_t)z * sC;
    half_t* Ch = (half_t*)Cp + (size_t)z * sC;
    unsigned char* C8 = (unsigned char*)Cp + (size_t)z * sC;

    const int tid = threadIdx.x;
    const int wv = tid >> 6, ln = tid & 63;
    const int bm = bxi * 256, bn = byi * BN;
    // BN=256: 2M x 4N (wave 128x64). BN=128: 4M x 2N (wave 64x64).
    const int wm = (BN == 256) ? (wv & 1) * 128 : (wv & 3) * 64;
    const int wn = (BN == 256) ? (wv >> 1) * 64 : (wv >> 2) * 64;

    // staging: 128 B/row, 8 lanes/row, 64 rows per call (512 threads)
    const int srow  = tid >> 3;
    const int scolB = ((tid & 7) ^ ((tid >> 3) & 7)) * 16;   // pre-swizzled chunk
    const unsigned char* Ag = A + (size_t)(bm + srow) * K * ES + scolB;
    const unsigned char* Bg = W + (size_t)(bn + srow) * K * ES + scolB;

    f32x4 acc[MTW][4] = {};
    f32x4 accd[MTW] = {};                          // PV: row-sum accumulator
    const long ONES8 = 0x3838383838383838L;        // 8 x e4m3(1.0)

    const int lane15 = ln & 15, quad = ln >> 4;
    const int sw = lane15 & 7;                     // read-side chunk XOR
    const int nIter = (K * ES) / 128;              // staged tiles (128 B rows)

    // stage call c of tile t into buffer slot b (c<4: A rows c*64.., else B)
    auto stageCall = [&](int b, int t, int c) {
        const size_t ko = (size_t)t * 128;
        if (c < 4)
            gl_lds16(Ag + (size_t)(c * 64) * K * ES + ko,
                     As + b * ASZ + c * 8192 + wv * 1024);
        else {
            const int cb = c - 4;
            gl_lds16(Bg + (size_t)(cb * 64) * K * ES + ko,
                     Bs + b * BSZ + cb * 8192 + wv * 1024);
        }
    };

#pragma unroll
    for (int c = 0; c < VM; ++c) stageCall(0, 0, c);

    for (int it = 0; it < nIter; ++it) {
        const int cur = it & 1;
        asm volatile("s_waitcnt vmcnt(0)" ::: "memory");
        __builtin_amdgcn_s_barrier();

        const unsigned char* Ab = As + cur * ASZ;
        const unsigned char* Bb = Bs + cur * BSZ;
        const bool pf = (it + 1 < nIter);

        if constexpr (ES == 2 && BN == 256) {      // f16, BN=256: 4 phases x16
#pragma unroll
            for (int ks = 0; ks < 2; ++ks) {
                half8 bF[4];
#pragma unroll
                for (int mq = 0; mq < 2; ++mq) {
                    const int cB = ((ks * 4 + quad) ^ sw) * 16;
                    half8 aF[4];
#pragma unroll
                    for (int i = 0; i < 4; ++i)
                        aF[i] = *(const half8*)(Ab + (wm + (mq * 4 + i) * 16 + lane15) * 128 + cB);
                    if (mq == 0)
#pragma unroll
                        for (int j = 0; j < 4; ++j)
                            bF[j] = *(const half8*)(Bb + (wn + j * 16 + lane15) * 128 + cB);
                    const int p = ks * 2 + mq;
                    if (pf)
#pragma unroll
                        for (int c = p * VM / PHS; c < (p + 1) * VM / PHS; ++c)
                            stageCall(cur ^ 1, it + 1, c);
                    __builtin_amdgcn_s_barrier();
                    __builtin_amdgcn_s_setprio(1);
#pragma unroll
                    for (int i = 0; i < 4; ++i)
#pragma unroll
                        for (int j = 0; j < 4; ++j)
                            acc[mq * 4 + i][j] = __builtin_amdgcn_mfma_f32_16x16x32_f16(
                                aF[i], bF[j], acc[mq * 4 + i][j], 0, 0, 0);
                    __builtin_amdgcn_s_setprio(0);
                }
            }
        } else if constexpr (ES == 2 && BN == 128) { // f16, BN=128: 2 phases x16
            // front-load ALL stage calls (HBM-latency cover; see header)
            if (pf)
#pragma unroll
                for (int c = 0; c < VM; ++c) stageCall(cur ^ 1, it + 1, c);
#pragma unroll
            for (int ks = 0; ks < 2; ++ks) {
                const int cB = ((ks * 4 + quad) ^ sw) * 16;
                half8 aF[4], bF[4];
#pragma unroll
                for (int i = 0; i < 4; ++i)
                    aF[i] = *(const half8*)(Ab + (wm + i * 16 + lane15) * 128 + cB);
#pragma unroll
                for (int j = 0; j < 4; ++j)
                    bF[j] = *(const half8*)(Bb + (wn + j * 16 + lane15) * 128 + cB);
                __builtin_amdgcn_s_barrier();
                __builtin_amdgcn_s_setprio(1);
#pragma unroll
                for (int i = 0; i < 4; ++i)
#pragma unroll
                    for (int j = 0; j < 4; ++j)
                        acc[i][j] = __builtin_amdgcn_mfma_f32_16x16x32_f16(
                            aF[i], bF[j], acc[i][j], 0, 0, 0);
                __builtin_amdgcn_s_setprio(0);
            }
        } else if constexpr (ES == 1 && BN == 256) { // fp8, BN=256: 8 phases x16
#pragma unroll
            for (int ks = 0; ks < 4; ++ks) {
                long bF8[4];
#pragma unroll
                for (int mq = 0; mq < 2; ++mq) {
                    const int cB = (((ks * 2 + (quad >> 1)) ^ sw) * 16) + (quad & 1) * 8;
                    long aF8[4];
#pragma unroll
                    for (int i = 0; i < 4; ++i)
                        aF8[i] = *(const long*)(Ab + (wm + (mq * 4 + i) * 16 + lane15) * 128 + cB);
                    if (mq == 0)
#pragma unroll
                        for (int j = 0; j < 4; ++j)
                            bF8[j] = *(const long*)(Bb + (wn + j * 16 + lane15) * 128 + cB);
                    const int p = ks * 2 + mq;
                    if (pf)
#pragma unroll
                        for (int c = p * VM / PHS; c < (p + 1) * VM / PHS; ++c)
                            stageCall(cur ^ 1, it + 1, c);
                    __builtin_amdgcn_s_barrier();
                    __builtin_amdgcn_s_setprio(1);
#pragma unroll
                    for (int i = 0; i < 4; ++i)
#pragma unroll
                        for (int j = 0; j < 4; ++j)
                            acc[mq * 4 + i][j] = __builtin_amdgcn_mfma_f32_16x16x32_fp8_fp8(
                                aF8[i], bF8[j], acc[mq * 4 + i][j], 0, 0, 0);
                    __builtin_amdgcn_s_setprio(0);
                }
            }
        } else {                                   // fp8, BN=128: 4 phases x(16+4)
#pragma unroll
            for (int ks = 0; ks < 4; ++ks) {
                const int cB = (((ks * 2 + (quad >> 1)) ^ sw) * 16) + (quad & 1) * 8;
                long aF8[4], bF8[4];
#pragma unroll
                for (int i = 0; i < 4; ++i)
                    aF8[i] = *(const long*)(Ab + (wm + i * 16 + lane15) * 128 + cB);
#pragma unroll
                for (int j = 0; j < 4; ++j)
                    bF8[j] = *(const long*)(Bb + (wn + j * 16 + lane15) * 128 + cB);
                const int p = ks;
                if (pf)
#pragma unroll
                    for (int c = p * VM / PHS; c < (p + 1) * VM / PHS; ++c)
                        stageCall(cur ^ 1, it + 1, c);
                __builtin_amdgcn_s_barrier();
                __builtin_amdgcn_s_setprio(1);
#pragma unroll
                for (int i = 0; i < 4; ++i) {
#pragma unroll
                    for (int j = 0; j < 4; ++j)
                        acc[i][j] = __builtin_amdgcn_mfma_f32_16x16x32_fp8_fp8(
                            aF8[i], bF8[j], acc[i][j], 0, 0, 0);
                    if (EPI == EPI_PV)             // row-sum = P . ones
                        accd[i] = __builtin_amdgcn_mfma_f32_16x16x32_fp8_fp8(
                            aF8[i], ONES8, accd[i], 0, 0, 0);
                }
                __builtin_amdgcn_s_setprio(0);
            }
        }
    }

    float invd[MTW][4];
    if (EPI == EPI_PV) {
#pragma unroll
        for (int i = 0; i < MTW; ++i)
#pragma unroll
            for (int r = 0; r < 4; ++r)
                invd[i][r] = 1.0f / accd[i][r];    // D[m][n]=rowsum(m), all lanes
    }

    // epilogue; C/D layout: col = lane&15, row = quad*4 + r
#pragma unroll
    for (int i = 0; i < MTW; ++i) {
        const int m0 = bm + wm + i * 16 + quad * 4;
#pragma unroll
        for (int j = 0; j < 4; ++j) {
            const int gn = bn + wn + j * 16 + lane15;
            if (EPI == EPI_QKV) {
                const int seg = gn >> 9, nn = gn & (DD - 1);
                if (seg == 2) {                    // V^T fp8, packed over rows (s)
                    unsigned int pk = 0;
#pragma unroll
                    for (int r = 0; r < 4; ++r)
                        pk |= (unsigned int)f2e4m3(acc[i][j][r] + biasV[nn]) << (8 * r);
                    const int b = m0 >> 11, s0 = m0 & (SS - 1);
                    *(unsigned int*)&Cv[((size_t)b * DD + nn) * SS + s0] = pk;
                } else {
                    const float bs = (seg == 0) ? bias[nn] : biasK[nn];
                    unsigned char* dst = (seg == 0) ? C8 : Ck;
#pragma unroll
                    for (int r = 0; r < 4; ++r)
                        dst[(size_t)(m0 + r) * DD + nn] = f2e4m3(acc[i][j][r] + bs);
                }
            } else {
#pragma unroll
                for (int r = 0; r < 4; ++r) {
                    const int gm = m0 + r;
                    float v = acc[i][j][r];
                    if (EPI == EPI_ATTN) {
                        int dist = gm - gn; if (dist < 0) dist = -dist;
                        v = __expf(fminf(v * alpha + bias[dist], 6.0f));
                        C8[(size_t)gm * N + gn] = f2e4m3(v);
                    } else if (EPI == EPI_PV) {
                        const size_t idx = (size_t)gm * N + gn;
                        Cf[idx] = v * invd[i][r] + Cf[idx];     // + x residual
                    } else if (EPI == EPI_RELU) {
                        Ch[(size_t)gm * N + gn] = (half_t)fmaxf(v + bias[gn], 0.0f);
                    } else {                        // EPI_RES
                        const size_t idx = (size_t)gm * N + gn;
                        Cf[idx] = v + bias[gn] + Cf[idx];
                    }
                }
            }
        }
    }
}

// ---------------- out = x @ out_w^T + out_b  (ODIM=1) ----------------
__global__ __launch_bounds__(256) void out_kernel(
    const float* __restrict__ x, const float* __restrict__ ow,
    const float* __restrict__ ob, float* __restrict__ out)
{
    int row = blockIdx.x * 4 + (threadIdx.x >> 6);
    int lane = threadIdx.x & 63;
    const float* p = x + (size_t)row * DD;
    float s = 0.f;
#pragma unroll
    for (int k = 0; k < 8; ++k) s += p[lane + 64 * k] * ow[lane + 64 * k];
#pragma unroll
    for (int off = 32; off; off >>= 1) s += __shfl_down(s, off);
    if (lane == 0) out[row] = s + ob[0];
}

// ---------------- launch ----------------
extern "C" void kernel_launch(void* const* d_in, const int* in_sizes, int n_in,
                              void* d_out, int out_size, void* d_ws, size_t ws_size,
                              hipStream_t stream)
{
    (void)in_sizes; (void)n_in; (void)out_size;
    const float* z     = (const float*)d_in[0];
    const float* c     = (const float*)d_in[1];
    const float* enc_w = (const float*)d_in[2];
    const float* enc_b = (const float*)d_in[3];
    const float* beta  = (const float*)d_in[4];
    const float* wq    = (const float*)d_in[5];
    const float* bq    = (const float*)d_in[6];
    const float* wk    = (const float*)d_in[7];
    const float* bk    = (const float*)d_in[8];
    const float* wv    = (const float*)d_in[9];
    const float* bv    = (const float*)d_in[10];
    const float* ln1w  = (const float*)d_in[11];
    const float* ln1b  = (const float*)d_in[12];
    const float* ln2w  = (const float*)d_in[13];
    const float* ln2b  = (const float*)d_in[14];
    const float* ff1w  = (const float*)d_in[15];
    const float* ff1b  = (const float*)d_in[16];
    const float* ff2w  = (const float*)d_in[17];
    const float* ff2b  = (const float*)d_in[18];
    const float* ow    = (const float*)d_in[19];
    const float* ob    = (const float*)d_in[20];

    const size_t BSD = (size_t)BB * SS * DD;   // 8.39M
    const size_t BSS = (size_t)BB * SS * SS;   // 33.6M
    const size_t NQ3 = (size_t)3 * DD * DD;    // 786432
    const size_t FF  = (size_t)FFD * DD;       // 1048576

    // Workspace layout. Big path (all-layer weight buffers): ~211 MB.
    char* p = (char*)d_ws;
    float*  x    = (float*)p;  p += BSD * 4;            // 33.55 MB
    half_t* xnh  = (half_t*)p; p += BSD * 2;            // 16.78 MB
    unsigned char* sch = (unsigned char*)p; p += BSS;   // 33.55 MB  fp8 exp-scores
    unsigned char* qh  = (unsigned char*)p; p += BSD;   // 8.39 MB
    unsigned char* kh  = (unsigned char*)p; p += BSD;   // 8.39 MB
    unsigned char* vth = (unsigned char*)p; p += BSD;   // 8.39 MB  [B][D][S]
    half_t* hh   = (half_t*)p; p += (size_t)BB * SS * FFD * 2;   // 67.11 MB
    float*  tbl  = (float*)p;  p += (size_t)LL * SS * 4;         // 48 KB
    half_t* wqkv6 = (half_t*)p;                                  // base of weights
    const size_t bigNeed = (size_t)(p - (char*)d_ws) + (size_t)LL * (NQ3 + 2 * FF) * 2;
    const bool big = (ws_size == 0) || (ws_size >= bigNeed);  // hoisted one-shot convert
    const size_t NL = big ? (size_t)LL : 1;                   // layers of weight storage
    half_t* f1h6 = wqkv6 + NL * NQ3;
    half_t* f2h6 = f1h6 + NL * FF;

    const float alpha = 0.044194173824159216f;      // 1/sqrt(512)
    const int BS = BB * SS;
    const long long sQ = (long long)SS * DD, sP = (long long)SS * SS,
                    sV = (long long)DD * SS;

    bias_table_kernel<<<LL * SS / 256, 256, 0, stream>>>(beta, tbl);
    encode_kernel<<<BS * DD / 256, 256, 0, stream>>>(z, c, enc_w, enc_b, x);

    if (big)    // one-shot vectorized conversion of ALL layer weights
        convert_all_kernel<<<LL * 2816, 256, 0, stream>>>(
            wq, wk, wv, ff1w, ff2w, wqkv6, f1h6, f2h6);

    for (int l = 0; l < LL; ++l) {
        half_t* wqkv_l = wqkv6 + (big ? (size_t)l * NQ3 : 0);
        half_t* f1h_l  = f1h6  + (big ? (size_t)l * FF  : 0);
        half_t* f2h_l  = f2h6  + (big ? (size_t)l * FF  : 0);
        if (!big)   // fallback: per-layer conversion into single buffers
            convert_layer_kernel<<<(int)((NQ3 + 2 * FF) / 256), 256, 0, stream>>>(
                wq + (size_t)l * DD * DD, wk + (size_t)l * DD * DD,
                wv + (size_t)l * DD * DD, ff1w + (size_t)l * FF,
                ff2w + (size_t)l * FF, wqkv_l, f1h_l, f2h_l);

        ln_kernel<<<BS, 256, 0, stream>>>(x, ln1w + l * DD, ln1b + l * DD, xnh);

        // fused QKV (fp16 in, fp8 out): 256x128 tiles, 768 blocks
        gemm256<half_t, 128, EPI_QKV><<<dim3(BS / 256, 12, 1), 512, 0, stream>>>(
            xnh, wqkv_l, bq + l * DD, qh, 1536, DD, 0, 0, 0, 0,
            bk + l * DD, bv + l * DD, kh, vth);

        // QK^T (fp8 x fp8) -> exp(s*alpha + cos-bias) as fp8; 256x256, XCD swz
        gemm256<unsigned char, 256, EPI_ATTN, 1><<<dim3(512, 1, 1), 512, 0, stream>>>(
            qh, kh, tbl + l * SS, sch, SS, DD, alpha, sQ, sQ, sP,
            nullptr, nullptr, nullptr, nullptr);

        // P @ V (fp8 x fp8), ones-MFMA denominator, +x residual; 256x128
        gemm256<unsigned char, 128, EPI_PV><<<dim3(SS / 256, DD / 128, BB), 512, 0, stream>>>(
            sch, vth, nullptr, x, DD, SS, 0, sP, sV, sQ,
            nullptr, nullptr, nullptr, nullptr);

        ln_ln_kernel<<<BS, 256, 0, stream>>>(x, ln1w + l * DD, ln1b + l * DD,
                                             ln2w + l * DD, ln2b + l * DD, xnh);

        // FFN: FF1 256x256 (512 blocks), FF2 256x128 (256 blocks)
        gemm256<half_t, 256, EPI_RELU><<<dim3(BS / 256, FFD / 256, 1), 512, 0, stream>>>(
            xnh, f1h_l, ff1b + l * FFD, hh, FFD, DD, 0, 0, 0, 0,
            nullptr, nullptr, nullptr, nullptr);
        gemm256<half_t, 128, EPI_RES><<<dim3(BS / 256, DD / 128, 1), 512, 0, stream>>>(
            hh, f2h_l, ff2b + l * DD, x, DD, FFD, 0, 0, 0, 0,
            nullptr, nullptr, nullptr, nullptr);
    }

    out_kernel<<<BS / 4, 256, 0, stream>>>(x, ow, ob, (float*)d_out);
}

// Round 14
// 1716.309 us; speedup vs baseline: 1.0971x; 1.0971x over previous
//
#include <hip/hip_runtime.h>
#include <hip/hip_fp8.h>
#include <math.h>

#define BB 8
#define SS 2048
#define DD 512
#define LL 6
#define FFD 2048   // 4*D

typedef _Float16 half_t;
typedef __attribute__((ext_vector_type(8))) _Float16 half8;
typedef __attribute__((ext_vector_type(4))) _Float16 half4;
typedef __attribute__((ext_vector_type(4))) float f32x4;

enum { EPI_NONE = 0, EPI_RELU = 2, EPI_RES = 3, EPI_ATTN = 4, EPI_QKV = 5, EPI_PV = 6 };

__device__ __forceinline__ unsigned char f2e4m3(float v) {
    __hip_fp8_e4m3 f(v);
    return f.__x;
}

// ---------------- async global->LDS, 16B per lane ----------------
__device__ __forceinline__ void gl_lds16(const void* g, void* l) {
    __builtin_amdgcn_global_load_lds(
        (const __attribute__((address_space(1))) unsigned int*)g,
        (__attribute__((address_space(3))) unsigned int*)l,
        16, 0, 0);
}

__device__ __forceinline__ void blockReduce2(float& a, float& b, float* sm) {
#pragma unroll
    for (int off = 32; off; off >>= 1) {
        a += __shfl_down(a, off);
        b += __shfl_down(b, off);
    }
    int lane = threadIdx.x & 63;
    int w = threadIdx.x >> 6;
    if (lane == 0) { sm[w] = a; sm[4 + w] = b; }
    __syncthreads();
    a = sm[0] + sm[1] + sm[2] + sm[3];
    b = sm[4] + sm[5] + sm[6] + sm[7];
    __syncthreads();
}

// ---------------- encoder ----------------
__global__ __launch_bounds__(256) void encode_kernel(
    const float* __restrict__ z, const float* __restrict__ c,
    const float* __restrict__ enc_w, const float* __restrict__ enc_b,
    float* __restrict__ x)
{
    int idx = blockIdx.x * 256 + threadIdx.x;
    int d  = idx & (DD - 1);
    int bs = idx >> 9;
    int s  = bs & (SS - 1);
    float v = z[bs] * enc_w[2 * d] + c[bs] * enc_w[2 * d + 1] + enc_b[d];
    float div = expf(-(float)(d & ~1) * (9.210340371976184f / 512.0f));
    float ang = (float)s * div;
    v += (d & 1) ? cosf(ang) : sinf(ang);
    x[idx] = v;
}

// ---- one-shot weight conversion, ALL layers, float4->half4 vectorized ----
// 720896 quads/layer: [0,196608) -> wqkv, then 262144 -> f1, 262144 -> f2.
__global__ __launch_bounds__(256) void convert_all_kernel(
    const float* __restrict__ wq, const float* __restrict__ wk,
    const float* __restrict__ wv, const float* __restrict__ f1,
    const float* __restrict__ f2, half_t* __restrict__ wqkv6,
    half_t* __restrict__ f1h6, half_t* __restrict__ f2h6)
{
    const int NQ = DD * DD;                      // 262144
    const int l = blockIdx.x / 2816;
    const int q = (blockIdx.x % 2816) * 256 + threadIdx.x;  // quad in layer
    const int j4 = q * 4;
    const float* src;
    half_t* dst;
    int j;
    if (j4 < 3 * NQ) {
        const int which = j4 >> 18;
        j = j4 & (NQ - 1);
        src = ((which == 0) ? wq : (which == 1) ? wk : wv) + (size_t)l * NQ;
        dst = wqkv6 + (size_t)l * 3 * NQ + which * NQ;
    } else {
        int k = j4 - 3 * NQ;
        if (k < FFD * DD) {
            j = k;
            src = f1 + (size_t)l * FFD * DD;
            dst = f1h6 + (size_t)l * FFD * DD;
        } else {
            j = k - FFD * DD;
            src = f2 + (size_t)l * DD * FFD;
            dst = f2h6 + (size_t)l * DD * FFD;
        }
    }
    f32x4 v = *(const f32x4*)(src + j);
    half4 h;
    h[0] = (half_t)v[0]; h[1] = (half_t)v[1];
    h[2] = (half_t)v[2]; h[3] = (half_t)v[3];
    *(half4*)(dst + j) = h;
}

// ------- fallback per-layer conversion (used only if ws_size is tight) -------
__global__ __launch_bounds__(256) void convert_layer_kernel(
    const float* __restrict__ wq, const float* __restrict__ wk,
    const float* __restrict__ wv, const float* __restrict__ f1,
    const float* __restrict__ f2, half_t* __restrict__ wqkv,
    half_t* __restrict__ f1h, half_t* __restrict__ f2h)
{
    const int NQ = DD * DD;                      // 262144
    int i = blockIdx.x * 256 + threadIdx.x;
    if (i < 3 * NQ) {
        int which = i >> 18, j = i & (NQ - 1);
        const float* s = (which == 0) ? wq : (which == 1) ? wk : wv;
        wqkv[i] = (half_t)s[j];
    } else {
        int k = i - 3 * NQ;
        if (k < FFD * DD) f1h[k] = (half_t)f1[k];
        else              f2h[k - FFD * DD] = (half_t)f2[k - FFD * DD];
    }
}

// ---------------- attention bias tables: tbl[l][dist] ----------------
__global__ __launch_bounds__(256) void bias_table_kernel(
    const float* __restrict__ beta, float* __restrict__ tbl)
{
    int i = blockIdx.x * 256 + threadIdx.x;   // L*2048
    int l = i >> 11, d = i & (SS - 1);
    tbl[i] = beta[2 * l] * cosf(0.2617993877991494f * d)
           + beta[2 * l + 1] * cosf(0.008726646259971648f * d);
}

// ---------------- LN: dst(half) = LN(src)*w + b ----------------
__global__ __launch_bounds__(256) void ln_kernel(
    const float* __restrict__ src, const float* __restrict__ w,
    const float* __restrict__ b, half_t* __restrict__ dst)
{
    __shared__ float sm[8];
    size_t row = blockIdx.x;
    const float* p = src + row * DD;
    int t = threadIdx.x;
    float v0 = p[t], v1 = p[t + 256];
    float s = v0 + v1, sq = v0 * v0 + v1 * v1;
    blockReduce2(s, sq, sm);
    float mean = s * (1.0f / DD);
    float var  = sq * (1.0f / DD) - mean * mean;
    float rs   = rsqrtf(var + 1e-5f);
    dst[row * DD + t]       = (half_t)((v0 - mean) * rs * w[t] + b[t]);
    dst[row * DD + t + 256] = (half_t)((v1 - mean) * rs * w[t + 256] + b[t + 256]);
}

// -------- fused: x = LN(x, w1,b1); xn(half) = LN(x', w2,b2) --------
__global__ __launch_bounds__(256) void ln_ln_kernel(
    float* __restrict__ x,
    const float* __restrict__ w1, const float* __restrict__ b1,
    const float* __restrict__ w2, const float* __restrict__ b2,
    half_t* __restrict__ xn)
{
    __shared__ float sm[8];
    size_t row = blockIdx.x;
    int t = threadIdx.x;
    float v0 = x[row * DD + t];
    float v1 = x[row * DD + t + 256];
    float s = v0 + v1, sq = v0 * v0 + v1 * v1;
    blockReduce2(s, sq, sm);
    float mean = s * (1.0f / DD);
    float var  = sq * (1.0f / DD) - mean * mean;
    float rs   = rsqrtf(var + 1e-5f);
    float y0 = (v0 - mean) * rs * w1[t] + b1[t];
    float y1 = (v1 - mean) * rs * w1[t + 256] + b1[t + 256];
    x[row * DD + t]       = y0;
    x[row * DD + t + 256] = y1;
    s = y0 + y1; sq = y0 * y0 + y1 * y1;
    blockReduce2(s, sq, sm);
    mean = s * (1.0f / DD);
    var  = sq * (1.0f / DD) - mean * mean;
    rs   = rsqrtf(var + 1e-5f);
    xn[row * DD + t]       = (half_t)((y0 - mean) * rs * w2[t] + b2[t]);
    xn[row * DD + t + 256] = (half_t)((y1 - mean) * rs * w2[t + 256] + b2[t + 256]);
}

// ------------- 256-row MFMA NT GEMM, 8-wave phase-split schedule -------------
// Round 14 = round 12 base (R13's staging front-load REVERTED: it regressed
// FF2 54->66 us, falsifying HBM-latency exposure; loads were fine spread)
// + ONE change: f16/BN=128 variant (FF2, QKV) drops its 2 per-phase PACING
// barriers. Within an iteration stage writes hit buf cur^1 while ds_reads
// hit buf cur -- no hazard; the iteration-top vmcnt(0)+s_barrier provides
// all required ordering (each wave's prior ds_reads complete before its
// consuming MFMAs issue, which precede its barrier arrival => WAR-safe).
// Rationale: barriers/phase-slot -- FF2/QKV 1.5 (highest) vs PV/FF1 1.25,
// ATTN 0.56; FF2/QKV are also the slowest per slot (~4050 / ~2680 cyc vs
// ~1900 universal). 8-wave lockstep at 1 block/CU makes each pacing barrier
// a full straggler re-sync; FF2 pays 96/dispatch.
// fp8 + BN=256 variants byte-identical to R12 (in-run controls).
// LDS XOR swizzle: row r's 16-B chunk c stored at c^(r&7); staging
// pre-swizzles the global chunk per lane; reads XOR with (row&7).
// EPI_QKV : fp16 in -> fp8 out: Q(+bias), K(+biasK) row-major, V^T(+biasV)
// EPI_ATTN: fp8 in -> fp8 out: exp(min(v*alpha + tbl[|m-n|], 6))
// EPI_PV  : fp8 in -> fp32: ones-MFMA denominator, v*inv + x residual in-place
// EPI_RELU: fp16 in -> fp16: relu(v + bias[n])
// EPI_RES : fp16 in -> fp32: v + bias[n] + C (in-place residual)
template<typename TIN, int BN, int EPI, int SWZ = 0>
__global__ __launch_bounds__(512) void gemm256(
    const void* __restrict__ Ap, const void* __restrict__ Wp,
    const float* __restrict__ bias, void* __restrict__ Cp,
    int N, int K, float alpha,
    long long sA, long long sW, long long sC,
    const float* __restrict__ biasK, const float* __restrict__ biasV,
    unsigned char* __restrict__ Ck, unsigned char* __restrict__ Cv)
{
    constexpr int ES  = (int)sizeof(TIN);          // 2 (f16) or 1 (fp8)
    constexpr int MTW = (BN == 128) ? 4 : 8;       // m-tiles per wave
    constexpr int ASZ = 256 * 128;                 // one A buffer: 32 KB
    constexpr int BSZ = BN * 128;                  // one B buffer: 32/16 KB
    constexpr int VM  = 4 + BN / 64;               // stage calls per tile
    constexpr int PHS = (BN == 256) ? ((ES == 2) ? 4 : 8) : ((ES == 2) ? 2 : 4);
    __shared__ __align__(16) unsigned char As[2 * ASZ];
    __shared__ __align__(16) unsigned char Bs[2 * BSZ];

    int bxi, byi, bzi;
    if (SWZ == 1) {                                // XCD-bijective, 512 blocks
        const int id = blockIdx.x;
        const int ss2 = (id & 7) * 64 + (id >> 3);
        bxi = ss2 & 7; byi = (ss2 >> 3) & 7; bzi = ss2 >> 6;
    } else { bxi = blockIdx.x; byi = blockIdx.y; bzi = blockIdx.z; }

    const int z = bzi;
    const unsigned char* A = (const unsigned char*)Ap + (size_t)z * sA * ES;
    const unsigned char* W = (const unsigned char*)Wp + (size_t)z * sW * ES;
    float*  Cf = (float*)Cp  + (size_t)z * sC;
    half_t* Ch = (half_t*)Cp + (size_t)z * sC;
    unsigned char* C8 = (unsigned char*)Cp + (size_t)z * sC;

    const int tid = threadIdx.x;
    const int wv = tid >> 6, ln = tid & 63;
    const int bm = bxi * 256, bn = byi * BN;
    // BN=256: 2M x 4N (wave 128x64). BN=128: 4M x 2N (wave 64x64).
    const int wm = (BN == 256) ? (wv & 1) * 128 : (wv & 3) * 64;
    const int wn = (BN == 256) ? (wv >> 1) * 64 : (wv >> 2) * 64;

    // staging: 128 B/row, 8 lanes/row, 64 rows per call (512 threads)
    const int srow  = tid >> 3;
    const int scolB = ((tid & 7) ^ ((tid >> 3) & 7)) * 16;   // pre-swizzled chunk
    const unsigned char* Ag = A + (size_t)(bm + srow) * K * ES + scolB;
    const unsigned char* Bg = W + (size_t)(bn + srow) * K * ES + scolB;

    f32x4 acc[MTW][4] = {};
    f32x4 accd[MTW] = {};                          // PV: row-sum accumulator
    const long ONES8 = 0x3838383838383838L;        // 8 x e4m3(1.0)

    const int lane15 = ln & 15, quad = ln >> 4;
    const int sw = lane15 & 7;                     // read-side chunk XOR
    const int nIter = (K * ES) / 128;              // staged tiles (128 B rows)

    // stage call c of tile t into buffer slot b (c<4: A rows c*64.., else B)
    auto stageCall = [&](int b, int t, int c) {
        const size_t ko = (size_t)t * 128;
        if (c < 4)
            gl_lds16(Ag + (size_t)(c * 64) * K * ES + ko,
                     As + b * ASZ + c * 8192 + wv * 1024);
        else {
            const int cb = c - 4;
            gl_lds16(Bg + (size_t)(cb * 64) * K * ES + ko,
                     Bs + b * BSZ + cb * 8192 + wv * 1024);
        }
    };

#pragma unroll
    for (int c = 0; c < VM; ++c) stageCall(0, 0, c);

    for (int it = 0; it < nIter; ++it) {
        const int cur = it & 1;
        asm volatile("s_waitcnt vmcnt(0)" ::: "memory");
        __builtin_amdgcn_s_barrier();

        const unsigned char* Ab = As + cur * ASZ;
        const unsigned char* Bb = Bs + cur * BSZ;
        const bool pf = (it + 1 < nIter);

        if constexpr (ES == 2 && BN == 256) {      // f16, BN=256: 4 phases x16
#pragma unroll
            for (int ks = 0; ks < 2; ++ks) {
                half8 bF[4];
#pragma unroll
                for (int mq = 0; mq < 2; ++mq) {
                    const int cB = ((ks * 4 + quad) ^ sw) * 16;
                    half8 aF[4];
#pragma unroll
                    for (int i = 0; i < 4; ++i)
                        aF[i] = *(const half8*)(Ab + (wm + (mq * 4 + i) * 16 + lane15) * 128 + cB);
                    if (mq == 0)
#pragma unroll
                        for (int j = 0; j < 4; ++j)
                            bF[j] = *(const half8*)(Bb + (wn + j * 16 + lane15) * 128 + cB);
                    const int p = ks * 2 + mq;
                    if (pf)
#pragma unroll
                        for (int c = p * VM / PHS; c < (p + 1) * VM / PHS; ++c)
                            stageCall(cur ^ 1, it + 1, c);
                    __builtin_amdgcn_s_barrier();
                    __builtin_amdgcn_s_setprio(1);
#pragma unroll
                    for (int i = 0; i < 4; ++i)
#pragma unroll
                        for (int j = 0; j < 4; ++j)
                            acc[mq * 4 + i][j] = __builtin_amdgcn_mfma_f32_16x16x32_f16(
                                aF[i], bF[j], acc[mq * 4 + i][j], 0, 0, 0);
                    __builtin_amdgcn_s_setprio(0);
                }
            }
        } else if constexpr (ES == 2 && BN == 128) { // f16, BN=128: 2 chunks x16
            // NO per-chunk pacing barriers (R14 change); spread staging as R12.
#pragma unroll
            for (int ks = 0; ks < 2; ++ks) {
                const int cB = ((ks * 4 + quad) ^ sw) * 16;
                half8 aF[4], bF[4];
#pragma unroll
                for (int i = 0; i < 4; ++i)
                    aF[i] = *(const half8*)(Ab + (wm + i * 16 + lane15) * 128 + cB);
#pragma unroll
                for (int j = 0; j < 4; ++j)
                    bF[j] = *(const half8*)(Bb + (wn + j * 16 + lane15) * 128 + cB);
                if (pf)
#pragma unroll
                    for (int c = ks * (VM / 2); c < (ks + 1) * (VM / 2); ++c)
                        stageCall(cur ^ 1, it + 1, c);
                __builtin_amdgcn_s_setprio(1);
#pragma unroll
                for (int i = 0; i < 4; ++i)
#pragma unroll
                    for (int j = 0; j < 4; ++j)
                        acc[i][j] = __builtin_amdgcn_mfma_f32_16x16x32_f16(
                            aF[i], bF[j], acc[i][j], 0, 0, 0);
                __builtin_amdgcn_s_setprio(0);
            }
        } else if constexpr (ES == 1 && BN == 256) { // fp8, BN=256: 8 phases x16
#pragma unroll
            for (int ks = 0; ks < 4; ++ks) {
                long bF8[4];
#pragma unroll
                for (int mq = 0; mq < 2; ++mq) {
                    const int cB = (((ks * 2 + (quad >> 1)) ^ sw) * 16) + (quad & 1) * 8;
                    long aF8[4];
#pragma unroll
                    for (int i = 0; i < 4; ++i)
                        aF8[i] = *(const long*)(Ab + (wm + (mq * 4 + i) * 16 + lane15) * 128 + cB);
                    if (mq == 0)
#pragma unroll
                        for (int j = 0; j < 4; ++j)
                            bF8[j] = *(const long*)(Bb + (wn + j * 16 + lane15) * 128 + cB);
                    const int p = ks * 2 + mq;
                    if (pf)
#pragma unroll
                        for (int c = p * VM / PHS; c < (p + 1) * VM / PHS; ++c)
                            stageCall(cur ^ 1, it + 1, c);
                    __builtin_amdgcn_s_barrier();
                    __builtin_amdgcn_s_setprio(1);
#pragma unroll
                    for (int i = 0; i < 4; ++i)
#pragma unroll
                        for (int j = 0; j < 4; ++j)
                            acc[mq * 4 + i][j] = __builtin_amdgcn_mfma_f32_16x16x32_fp8_fp8(
                                aF8[i], bF8[j], acc[mq * 4 + i][j], 0, 0, 0);
                    __builtin_amdgcn_s_setprio(0);
                }
            }
        } else {                                   // fp8, BN=128: 4 phases x(16+4)
#pragma unroll
            for (int ks = 0; ks < 4; ++ks) {
                const int cB = (((ks * 2 + (quad >> 1)) ^ sw) * 16) + (quad & 1) * 8;
                long aF8[4], bF8[4];
#pragma unroll
                for (int i = 0; i < 4; ++i)
                    aF8[i] = *(const long*)(Ab + (wm + i * 16 + lane15) * 128 + cB);
#pragma unroll
                for (int j = 0; j < 4; ++j)
                    bF8[j] = *(const long*)(Bb + (wn + j * 16 + lane15) * 128 + cB);
                const int p = ks;
                if (pf)
#pragma unroll
                    for (int c = p * VM / PHS; c < (p + 1) * VM / PHS; ++c)
                        stageCall(cur ^ 1, it + 1, c);
                __builtin_amdgcn_s_barrier();
                __builtin_amdgcn_s_setprio(1);
#pragma unroll
                for (int i = 0; i < 4; ++i) {
#pragma unroll
                    for (int j = 0; j < 4; ++j)
                        acc[i][j] = __builtin_amdgcn_mfma_f32_16x16x32_fp8_fp8(
                            aF8[i], bF8[j], acc[i][j], 0, 0, 0);
                    if (EPI == EPI_PV)             // row-sum = P . ones
                        accd[i] = __builtin_amdgcn_mfma_f32_16x16x32_fp8_fp8(
                            aF8[i], ONES8, accd[i], 0, 0, 0);
                }
                __builtin_amdgcn_s_setprio(0);
            }
        }
    }

    float invd[MTW][4];
    if (EPI == EPI_PV) {
#pragma unroll
        for (int i = 0; i < MTW; ++i)
#pragma unroll
            for (int r = 0; r < 4; ++r)
                invd[i][r] = 1.0f / accd[i][r];    // D[m][n]=rowsum(m), all lanes
    }

    // epilogue; C/D layout: col = lane&15, row = quad*4 + r
#pragma unroll
    for (int i = 0; i < MTW; ++i) {
        const int m0 = bm + wm + i * 16 + quad * 4;
#pragma unroll
        for (int j = 0; j < 4; ++j) {
            const int gn = bn + wn + j * 16 + lane15;
            if (EPI == EPI_QKV) {
                const int seg = gn >> 9, nn = gn & (DD - 1);
                if (seg == 2) {                    // V^T fp8, packed over rows (s)
                    unsigned int pk = 0;
#pragma unroll
                    for (int r = 0; r < 4; ++r)
                        pk |= (unsigned int)f2e4m3(acc[i][j][r] + biasV[nn]) << (8 * r);
                    const int b = m0 >> 11, s0 = m0 & (SS - 1);
                    *(unsigned int*)&Cv[((size_t)b * DD + nn) * SS + s0] = pk;
                } else {
                    const float bs = (seg == 0) ? bias[nn] : biasK[nn];
                    unsigned char* dst = (seg == 0) ? C8 : Ck;
#pragma unroll
                    for (int r = 0; r < 4; ++r)
                        dst[(size_t)(m0 + r) * DD + nn] = f2e4m3(acc[i][j][r] + bs);
                }
            } else {
#pragma unroll
                for (int r = 0; r < 4; ++r) {
                    const int gm = m0 + r;
                    float v = acc[i][j][r];
                    if (EPI == EPI_ATTN) {
                        int dist = gm - gn; if (dist < 0) dist = -dist;
                        v = __expf(fminf(v * alpha + bias[dist], 6.0f));
                        C8[(size_t)gm * N + gn] = f2e4m3(v);
                    } else if (EPI == EPI_PV) {
                        const size_t idx = (size_t)gm * N + gn;
                        Cf[idx] = v * invd[i][r] + Cf[idx];     // + x residual
                    } else if (EPI == EPI_RELU) {
                        Ch[(size_t)gm * N + gn] = (half_t)fmaxf(v + bias[gn], 0.0f);
                    } else {                        // EPI_RES
                        const size_t idx = (size_t)gm * N + gn;
                        Cf[idx] = v + bias[gn] + Cf[idx];
                    }
                }
            }
        }
    }
}

// ---------------- out = x @ out_w^T + out_b  (ODIM=1) ----------------
__global__ __launch_bounds__(256) void out_kernel(
    const float* __restrict__ x, const float* __restrict__ ow,
    const float* __restrict__ ob, float* __restrict__ out)
{
    int row = blockIdx.x * 4 + (threadIdx.x >> 6);
    int lane = threadIdx.x & 63;
    const float* p = x + (size_t)row * DD;
    float s = 0.f;
#pragma unroll
    for (int k = 0; k < 8; ++k) s += p[lane + 64 * k] * ow[lane + 64 * k];
#pragma unroll
    for (int off = 32; off; off >>= 1) s += __shfl_down(s, off);
    if (lane == 0) out[row] = s + ob[0];
}

// ---------------- launch ----------------
extern "C" void kernel_launch(void* const* d_in, const int* in_sizes, int n_in,
                              void* d_out, int out_size, void* d_ws, size_t ws_size,
                              hipStream_t stream)
{
    (void)in_sizes; (void)n_in; (void)out_size;
    const float* z     = (const float*)d_in[0];
    const float* c     = (const float*)d_in[1];
    const float* enc_w = (const float*)d_in[2];
    const float* enc_b = (const float*)d_in[3];
    const float* beta  = (const float*)d_in[4];
    const float* wq    = (const float*)d_in[5];
    const float* bq    = (const float*)d_in[6];
    const float* wk    = (const float*)d_in[7];
    const float* bk    = (const float*)d_in[8];
    const float* wv    = (const float*)d_in[9];
    const float* bv    = (const float*)d_in[10];
    const float* ln1w  = (const float*)d_in[11];
    const float* ln1b  = (const float*)d_in[12];
    const float* ln2w  = (const float*)d_in[13];
    const float* ln2b  = (const float*)d_in[14];
    const float* ff1w  = (const float*)d_in[15];
    const float* ff1b  = (const float*)d_in[16];
    const float* ff2w  = (const float*)d_in[17];
    const float* ff2b  = (const float*)d_in[18];
    const float* ow    = (const float*)d_in[19];
    const float* ob    = (const float*)d_in[20];

    const size_t BSD = (size_t)BB * SS * DD;   // 8.39M
    const size_t BSS = (size_t)BB * SS * SS;   // 33.6M
    const size_t NQ3 = (size_t)3 * DD * DD;    // 786432
    const size_t FF  = (size_t)FFD * DD;       // 1048576

    // Workspace layout. Big path (all-layer weight buffers): ~211 MB.
    char* p = (char*)d_ws;
    float*  x    = (float*)p;  p += BSD * 4;            // 33.55 MB
    half_t* xnh  = (half_t*)p; p += BSD * 2;            // 16.78 MB
    unsigned char* sch = (unsigned char*)p; p += BSS;   // 33.55 MB  fp8 exp-scores
    unsigned char* qh  = (unsigned char*)p; p += BSD;   // 8.39 MB
    unsigned char* kh  = (unsigned char*)p; p += BSD;   // 8.39 MB
    unsigned char* vth = (unsigned char*)p; p += BSD;   // 8.39 MB  [B][D][S]
    half_t* hh   = (half_t*)p; p += (size_t)BB * SS * FFD * 2;   // 67.11 MB
    float*  tbl  = (float*)p;  p += (size_t)LL * SS * 4;         // 48 KB
    half_t* wqkv6 = (half_t*)p;                                  // base of weights
    const size_t bigNeed = (size_t)(p - (char*)d_ws) + (size_t)LL * (NQ3 + 2 * FF) * 2;
    const bool big = (ws_size == 0) || (ws_size >= bigNeed);  // hoisted one-shot convert
    const size_t NL = big ? (size_t)LL : 1;                   // layers of weight storage
    half_t* f1h6 = wqkv6 + NL * NQ3;
    half_t* f2h6 = f1h6 + NL * FF;

    const float alpha = 0.044194173824159216f;      // 1/sqrt(512)
    const int BS = BB * SS;
    const long long sQ = (long long)SS * DD, sP = (long long)SS * SS,
                    sV = (long long)DD * SS;

    bias_table_kernel<<<LL * SS / 256, 256, 0, stream>>>(beta, tbl);
    encode_kernel<<<BS * DD / 256, 256, 0, stream>>>(z, c, enc_w, enc_b, x);

    if (big)    // one-shot vectorized conversion of ALL layer weights
        convert_all_kernel<<<LL * 2816, 256, 0, stream>>>(
            wq, wk, wv, ff1w, ff2w, wqkv6, f1h6, f2h6);

    for (int l = 0; l < LL; ++l) {
        half_t* wqkv_l = wqkv6 + (big ? (size_t)l * NQ3 : 0);
        half_t* f1h_l  = f1h6  + (big ? (size_t)l * FF  : 0);
        half_t* f2h_l  = f2h6  + (big ? (size_t)l * FF  : 0);
        if (!big)   // fallback: per-layer conversion into single buffers
            convert_layer_kernel<<<(int)((NQ3 + 2 * FF) / 256), 256, 0, stream>>>(
                wq + (size_t)l * DD * DD, wk + (size_t)l * DD * DD,
                wv + (size_t)l * DD * DD, ff1w + (size_t)l * FF,
                ff2w + (size_t)l * FF, wqkv_l, f1h_l, f2h_l);

        ln_kernel<<<BS, 256, 0, stream>>>(x, ln1w + l * DD, ln1b + l * DD, xnh);

        // fused QKV (fp16 in, fp8 out): 256x128 tiles, 768 blocks
        gemm256<half_t, 128, EPI_QKV><<<dim3(BS / 256, 12, 1), 512, 0, stream>>>(
            xnh, wqkv_l, bq + l * DD, qh, 1536, DD, 0, 0, 0, 0,
            bk + l * DD, bv + l * DD, kh, vth);

        // QK^T (fp8 x fp8) -> exp(s*alpha + cos-bias) as fp8; 256x256, XCD swz
        gemm256<unsigned char, 256, EPI_ATTN, 1><<<dim3(512, 1, 1), 512, 0, stream>>>(
            qh, kh, tbl + l * SS, sch, SS, DD, alpha, sQ, sQ, sP,
            nullptr, nullptr, nullptr, nullptr);

        // P @ V (fp8 x fp8), ones-MFMA denominator, +x residual; 256x128
        gemm256<unsigned char, 128, EPI_PV><<<dim3(SS / 256, DD / 128, BB), 512, 0, stream>>>(
            sch, vth, nullptr, x, DD, SS, 0, sP, sV, sQ,
            nullptr, nullptr, nullptr, nullptr);

        ln_ln_kernel<<<BS, 256, 0, stream>>>(x, ln1w + l * DD, ln1b + l * DD,
                                             ln2w + l * DD, ln2b + l * DD, xnh);

        // FFN: FF1 256x256 (512 blocks), FF2 256x128 (256 blocks)
        gemm256<half_t, 256, EPI_RELU><<<dim3(BS / 256, FFD / 256, 1), 512, 0, stream>>>(
            xnh, f1h_l, ff1b + l * FFD, hh, FFD, DD, 0, 0, 0, 0,
            nullptr, nullptr, nullptr, nullptr);
        gemm256<half_t, 128, EPI_RES><<<dim3(BS / 256, DD / 128, 1), 512, 0, stream>>>(
            hh, f2h_l, ff2b + l * DD, x, DD, FFD, 0, 0, 0, 0,
            nullptr, nullptr, nullptr, nullptr);
    }

    out_kernel<<<BS / 4, 256, 0, stream>>>(x, ow, ob, (float*)d_out);
}